// Round 11
// baseline (763.302 us; speedup 1.0000x reference)
//
#include <hip/hip_runtime.h>

typedef _Float16 f16x8 __attribute__((ext_vector_type(8)));
typedef _Float16 f16x4 __attribute__((ext_vector_type(4)));
typedef float    f32x4 __attribute__((ext_vector_type(4)));

#define TT 4
#define BB 32
#define CC 384
#define NN 256

// ---- ws layout (bytes) ----
// x0f f16 frag-major [(t*32+b)*16+n16][12 kc][64 lane][8] : 0        .. 25165824
// x1f                                                     : 25165824 .. 50331648
// wsp f16 frag-major weights [q0,q1,k0,k1,p0,p1], each
//     [288 frag = h*36+dt*12+kc][64 lane][8] = 147456 el  : 50331648 .. 52101120
//     (p0/p1 K-columns permuted to y's channel order)
// y   f16 frag-major [(t*32+b)*16+n16][12 kc][64][8]      : 52101120 .. 77266944
#define WS_X1   25165824
#define WS_WSP  50331648
#define WS_Y    52101120
#define WS_NEED 77266944

// ---------------------------------------------------------------------------
// prep (merged): blocks 0..3071 = x transpose+split; 3072..3287 = weights.
// (round-9/10 proven version, verbatim)
// ---------------------------------------------------------------------------
__global__ __launch_bounds__(256) void prep(
    const float* __restrict__ x,
    const float* __restrict__ qw, const float* __restrict__ kw,
    const float* __restrict__ pw,
    _Float16* __restrict__ x0, _Float16* __restrict__ x1,
    _Float16* __restrict__ wsp)
{
    __shared__ float xs[64 * 65];
    const int tid = threadIdx.x;
    int bid = blockIdx.x;

    if (bid >= 3072) {
        // ---- weight prep: frag-major f16 hi/lo tables ----
        int gid   = (bid - 3072) * 256 + tid;        // 0..55295
        int which = gid / 18432;                     // 0=q 1=k 2=p
        int sid   = gid % 18432;
        int frag  = sid >> 6;                        // 0..287
        int lane  = sid & 63;
        int h  = frag / 36;
        int rm = frag % 36;
        int dt = rm / 12, kc = rm % 12;
        int m16 = lane & 15, quad = lane >> 4;
        int d = h * 48 + dt * 16 + m16;

        const float* src = (which == 0) ? qw : (which == 1) ? kw : pw;
        _Float16* o0 = wsp + (size_t)which * 294912;
        _Float16* o1 = o0 + 147456;

        f16x8 h0, h1;
#pragma unroll
        for (int jj = 0; jj < 8; ++jj) {
            int cp = kc * 32 + quad * 8 + jj;
            int c;
            if (which == 2) {
                int hp = cp / 48, w = cp % 48;
                int qp = w / 12, r12 = w % 12;
                int sl = r12 >> 2, rr = r12 & 3;
                c = hp * 48 + sl * 16 + qp * 4 + rr;  // inverse permutation
            } else {
                c = cp;
            }
            float v = src[d * CC + c];
            _Float16 a = (_Float16)v;
            h0[jj] = a; h1[jj] = (_Float16)(v - (float)a);
        }
        size_t off = (size_t)frag * 512 + lane * 8;
        *(f16x8*)(o0 + off) = h0;
        *(f16x8*)(o1 + off) = h1;
        return;
    }

    // ---- x prep: [t][b][c][n] fp32 -> frag-major f16 hi/lo ----
    int tb = bid / 24, r = bid % 24;
    int c0 = (r >> 2) * 64, n0 = (r & 3) * 64;

#pragma unroll
    for (int p = 0; p < 4; ++p) {
        int c  = (tid >> 4) + p * 16;
        int nl = (tid & 15) * 4;
        float4 v = *(const float4*)&x[((size_t)tb * CC + c0 + c) * NN + n0 + nl];
        *(float4*)&xs[c * 65 + nl] = v;
    }
    __syncthreads();
#pragma unroll
    for (int p = 0; p < 2; ++p) {
        int sid  = p * 256 + tid;
        int frag = sid >> 6;
        int lane = sid & 63;
        int kcl  = frag & 1, n16l = frag >> 1;
        int m16 = lane & 15, quad = lane >> 4;
        int n_local = n16l * 16 + m16;
        int c_local = kcl * 32 + quad * 8;
        f16x8 h0, h1;
#pragma unroll
        for (int jj = 0; jj < 8; ++jj) {
            float v = xs[(c_local + jj) * 65 + n_local];
            _Float16 a = (_Float16)v;
            h0[jj] = a; h1[jj] = (_Float16)(v - (float)a);
        }
        size_t gf = ((size_t)tb * 16 + (n0 >> 4) + n16l) * 12 + (c0 >> 5) + kcl;
        size_t off = gf * 512 + lane * 8;
        *(f16x8*)(x0 + off) = h0;
        *(f16x8*)(x1 + off) = h1;
    }
}

// ---- qk helpers (round-8 style, t-dimension = 2 per pass) ----
__device__ __forceinline__ void qk_loadx2(
    const _Float16* __restrict__ x0, const _Float16* __restrict__ x1,
    const size_t* fx, int kc, f16x8 bx[2][2])
{
#pragma unroll
    for (int t2 = 0; t2 < 2; ++t2) {
        bx[t2][0] = *(const f16x8*)(x0 + fx[t2] + kc * 512);
        bx[t2][1] = *(const f16x8*)(x1 + fx[t2] + kc * 512);
    }
}

__device__ __forceinline__ void qk_step2(
    const _Float16* __restrict__ wq0, const _Float16* __restrict__ wq1,
    const _Float16* __restrict__ wk0, const _Float16* __restrict__ wk1,
    size_t fwb, int kc, const f16x8 bx[2][2],
    f32x4 aq[2][3], f32x4 ak[2][3])
{
#pragma unroll
    for (int dt = 0; dt < 3; ++dt) {
        size_t wo = fwb + (size_t)(dt * 12 + kc) * 512;
        f16x8 q0 = *(const f16x8*)(wq0 + wo);
        f16x8 q1 = *(const f16x8*)(wq1 + wo);
        f16x8 k0 = *(const f16x8*)(wk0 + wo);
        f16x8 k1 = *(const f16x8*)(wk1 + wo);
#pragma unroll
        for (int t2 = 0; t2 < 2; ++t2) {
            f32x4 cq = aq[t2][dt];
            cq = __builtin_amdgcn_mfma_f32_16x16x32_f16(q0, bx[t2][0], cq, 0, 0, 0);
            cq = __builtin_amdgcn_mfma_f32_16x16x32_f16(q1, bx[t2][0], cq, 0, 0, 0);
            cq = __builtin_amdgcn_mfma_f32_16x16x32_f16(q0, bx[t2][1], cq, 0, 0, 0);
            aq[t2][dt] = cq;
            f32x4 ck = ak[t2][dt];
            ck = __builtin_amdgcn_mfma_f32_16x16x32_f16(k0, bx[t2][0], ck, 0, 0, 0);
            ck = __builtin_amdgcn_mfma_f32_16x16x32_f16(k1, bx[t2][0], ck, 0, 0, 0);
            ck = __builtin_amdgcn_mfma_f32_16x16x32_f16(k0, bx[t2][1], ck, 0, 0, 0);
            ak[t2][dt] = ck;
        }
    }
}

// ---------------------------------------------------------------------------
// Kernel A: q/k GEMM + BN + LIF + head-sum + attn LIF + y=attn*k (frag-major)
// Round-8 structure with t split into two passes of 2 (acc halved) ->
// __launch_bounds__(256,3): 3 waves/SIMD. LIF state carried across passes.
// ---------------------------------------------------------------------------
__global__ __launch_bounds__(256, 3) void qk_mfma(
    const _Float16* __restrict__ x0, const _Float16* __restrict__ x1,
    const _Float16* __restrict__ wsp,
    const float* __restrict__ qg, const float* __restrict__ qbe,
    const float* __restrict__ qm, const float* __restrict__ qva,
    const float* __restrict__ kg, const float* __restrict__ kbe,
    const float* __restrict__ km, const float* __restrict__ kva,
    _Float16* __restrict__ y)
{
    const int tid  = threadIdx.x;
    const int wave = tid >> 6;
    const int lane = tid & 63;
    const int m16  = lane & 15;
    const int quad = lane >> 4;

    int bid = blockIdx.x;
    int r   = bid & 7;
    int hh  = (bid >> 3) & 1;
    int qq  = bid >> 4;                 // 0..63
    int j   = qq * 8 + r;               // 0..511
    int b   = j >> 4;
    int n16 = j & 15;

    const int head = hh * 4 + wave;

    const _Float16* wq0 = wsp;
    const _Float16* wq1 = wsp + 147456;
    const _Float16* wk0 = wsp + 2 * 147456;
    const _Float16* wk1 = wsp + 3 * 147456;

    size_t fxb[4];
#pragma unroll
    for (int t = 0; t < 4; ++t)
        fxb[t] = (((size_t)(t * BB + b) * 16 + n16) * 12) * 512 + lane * 8;
    size_t fwb = ((size_t)head * 36) * 512 + lane * 8;

    // persistent LIF state across both tp passes
    f32x4 vq[3], vk[3];
    float va = 0.f;
#pragma unroll
    for (int dt = 0; dt < 3; ++dt) {
        vq[dt] = (f32x4){0.f, 0.f, 0.f, 0.f};
        vk[dt] = (f32x4){0.f, 0.f, 0.f, 0.f};
    }

    for (int tp = 0; tp < 2; ++tp) {
        const size_t* fx = &fxb[tp * 2];
        f32x4 aq[2][3], ak[2][3];
#pragma unroll
        for (int t2 = 0; t2 < 2; ++t2)
#pragma unroll
            for (int dt = 0; dt < 3; ++dt) {
                aq[t2][dt] = (f32x4){0.f, 0.f, 0.f, 0.f};
                ak[t2][dt] = (f32x4){0.f, 0.f, 0.f, 0.f};
            }

        // software pipeline: ping-pong x prefetch, fully unrolled (12 kc)
        f16x8 bxA[2][2], bxB[2][2];
        qk_loadx2(x0, x1, fx, 0, bxA);
#pragma unroll
        for (int kc2 = 0; kc2 < 6; ++kc2) {
            qk_loadx2(x0, x1, fx, 2 * kc2 + 1, bxB);
            qk_step2(wq0, wq1, wk0, wk1, fwb, 2 * kc2, bxA, aq, ak);
            if (kc2 < 5)
                qk_loadx2(x0, x1, fx, 2 * kc2 + 2, bxA);
            qk_step2(wq0, wq1, wk0, wk1, fwb, 2 * kc2 + 1, bxB, aq, ak);
        }

        // ---- epilogue for this pass: sequential LIF over its 2 t ----
#pragma unroll
        for (int t2 = 0; t2 < 2; ++t2) {
            int t = tp * 2 + t2;
            float psum = 0.f;
            f32x4 ks[3];
#pragma unroll
            for (int dt = 0; dt < 3; ++dt) {
                int doff = head * 48 + dt * 16 + quad * 4;
                f32x4 gq  = *(const f32x4*)(qg + doff);
                f32x4 bq  = *(const f32x4*)(qbe + doff);
                f32x4 mq  = *(const f32x4*)(qm + doff);
                f32x4 vq_ = *(const f32x4*)(qva + doff);
                f32x4 gk_ = *(const f32x4*)(kg + doff);
                f32x4 bk_ = *(const f32x4*)(kbe + doff);
                f32x4 mk_ = *(const f32x4*)(km + doff);
                f32x4 vk_ = *(const f32x4*)(kva + doff);
#pragma unroll
                for (int rr = 0; rr < 4; ++rr) {
                    float invq = gq[rr] / sqrtf(vq_[rr] + 1e-5f);
                    float invk = gk_[rr] / sqrtf(vk_[rr] + 1e-5f);
                    float bnq = (aq[t2][dt][rr] - mq[rr]) * invq + bq[rr];
                    float hq  = vq[dt][rr] + (bnq - vq[dt][rr]) * 0.5f;
                    float sq  = (hq - 1.0f >= 0.0f) ? 1.0f : 0.0f;
                    vq[dt][rr] = hq * (1.0f - sq);
                    psum += sq;
                    float bnk = (ak[t2][dt][rr] - mk_[rr]) * invk + bk_[rr];
                    float hk  = vk[dt][rr] + (bnk - vk[dt][rr]) * 0.5f;
                    float sk  = (hk - 1.0f >= 0.0f) ? 1.0f : 0.0f;
                    vk[dt][rr] = hk * (1.0f - sk);
                    ks[dt][rr] = sk;
                }
            }
            psum += __shfl_xor(psum, 16, 64);     // 4 quads = all 48 d
            psum += __shfl_xor(psum, 32, 64);
            float ha = va + (psum - va) * 0.5f;
            float sa = (ha - 0.5f >= 0.0f) ? 1.0f : 0.0f;
            va = ha * (1.0f - sa);
            float attn = sa;
            // y store into frag-major layout (round-6/8 proven pattern)
            size_t ybase = (((size_t)(t * BB + b) * 16 + n16) * 12) * 512;
#pragma unroll
            for (int dt = 0; dt < 3; ++dt) {
                int c   = head * 48 + quad * 12 + dt * 4;
                int kcy = c >> 5;
                int qp  = (c & 31) >> 3;
                int jj  = c & 7;
                f16x4 hv;
#pragma unroll
                for (int rr = 0; rr < 4; ++rr)
                    hv[rr] = (_Float16)(attn * ks[dt][rr]);
                *(f16x4*)(y + ybase + (size_t)kcy * 512 + (m16 + 16 * qp) * 8 + jj) = hv;
            }
        }
    }
}

// ---- proj macros (round-9 proven version) ----
#define PJ_LOADY(dst, kcv)                                                   \
    {                                                                        \
        _Pragma("unroll")                                                    \
        for (int t = 0; t < 4; ++t)                                          \
            dst[t] = *(const f16x8*)(pyb[t] + (kcv) * 512 + lo);             \
    }

#define PJ_STEP(kcv, byv)                                                    \
    {                                                                        \
        f16x8 w[2][3];                                                       \
        _Pragma("unroll")                                                    \
        for (int sp = 0; sp < 2; ++sp)                                       \
            _Pragma("unroll")                                                \
            for (int dt = 0; dt < 3; ++dt)                                   \
                w[sp][dt] = *(const f16x8*)(pwt[sp] +                        \
                    (dt * 12 + (kcv)) * 512 + lo);                           \
        _Pragma("unroll")                                                    \
        for (int dt = 0; dt < 3; ++dt) {                                     \
            _Pragma("unroll")                                                \
            for (int t = 0; t < 4; ++t) {                                    \
                f32x4 c = acc[t][dt];                                        \
                c = __builtin_amdgcn_mfma_f32_16x16x32_f16(w[0][dt], byv[t], c, 0, 0, 0); \
                c = __builtin_amdgcn_mfma_f32_16x16x32_f16(w[1][dt], byv[t], c, 0, 0, 0); \
                acc[t][dt] = c;                                              \
            }                                                                \
        }                                                                    \
    }

// ---------------------------------------------------------------------------
// Kernel B: proj GEMM (frag-major) + bias + BN + LIF -> fp32 spikes.
// Round-9 proven tiling (4 waves = 4 d-tiles, shared n16 -> 4x y L1 reuse),
// bumped to 3 waves/SIMD.
// ---------------------------------------------------------------------------
__global__ __launch_bounds__(256, 3) void proj_mfma(
    const _Float16* __restrict__ y,
    const _Float16* __restrict__ pw0, const _Float16* __restrict__ pw1,
    const float* __restrict__ pg, const float* __restrict__ pbe,
    const float* __restrict__ pm, const float* __restrict__ pva,
    const float* __restrict__ pbias, float* __restrict__ out)
{
    const int tid  = threadIdx.x;
    const int wave = tid >> 6;
    const int lane = tid & 63;
    const int m16  = lane & 15;
    const int quad = lane >> 4;
    const int lo   = lane * 8;

    int bid = blockIdx.x;
    int r   = bid & 7;
    int dgg = (bid >> 3) & 1;
    int qq  = bid >> 4;
    int j   = qq * 8 + r;
    int b   = j >> 4;
    int n16 = j & 15;

    const int dw = dgg * 4 + wave;       // 0..7, d-tile of 48
    const int d0 = dw * 48;

    const _Float16* pyb[4];
#pragma unroll
    for (int t = 0; t < 4; ++t)
        pyb[t] = y + (((size_t)(t * BB + b) * 16 + n16) * 12) * 512;
    const _Float16* pwt[2];
    pwt[0] = pw0 + (size_t)dw * 36 * 512;
    pwt[1] = pw1 + (size_t)dw * 36 * 512;

    f32x4 acc[4][3];
#pragma unroll
    for (int t = 0; t < 4; ++t)
#pragma unroll
        for (int dt = 0; dt < 3; ++dt)
            acc[t][dt] = (f32x4){0.f, 0.f, 0.f, 0.f};

    f16x8 byA[4], byB[4];
    PJ_LOADY(byA, 0)
#pragma unroll
    for (int kc2 = 0; kc2 < 6; ++kc2) {
        PJ_LOADY(byB, 2 * kc2 + 1)
        PJ_STEP(2 * kc2, byA)
        if (kc2 < 5)
            PJ_LOADY(byA, 2 * kc2 + 2)
        PJ_STEP(2 * kc2 + 1, byB)
    }

    // epilogue: bias + BN + LIF (sequential t), store fp32 spikes
    f32x4 vv[3];
#pragma unroll
    for (int dt = 0; dt < 3; ++dt) vv[dt] = (f32x4){0.f, 0.f, 0.f, 0.f};
#pragma unroll
    for (int dt = 0; dt < 3; ++dt) {
        int doff = d0 + dt * 16 + quad * 4;
        f32x4 g_  = *(const f32x4*)(pg + doff);
        f32x4 be  = *(const f32x4*)(pbe + doff);
        f32x4 mu  = *(const f32x4*)(pm + doff);
        f32x4 va_ = *(const f32x4*)(pva + doff);
        f32x4 bi  = *(const f32x4*)(pbias + doff);
        float inv[4];
#pragma unroll
        for (int rr = 0; rr < 4; ++rr)
            inv[rr] = g_[rr] / sqrtf(va_[rr] + 1e-5f);
#pragma unroll
        for (int t = 0; t < 4; ++t) {
#pragma unroll
            for (int rr = 0; rr < 4; ++rr) {
                float z  = acc[t][dt][rr] + bi[rr];
                float bn = (z - mu[rr]) * inv[rr] + be[rr];
                float h  = vv[dt][rr] + (bn - vv[dt][rr]) * 0.5f;
                float sp = (h - 1.0f >= 0.0f) ? 1.0f : 0.0f;
                vv[dt][rr] = h * (1.0f - sp);
                out[((size_t)(t * BB + b) * CC + doff + rr) * NN +
                    n16 * 16 + m16] = sp;
            }
        }
    }
}

// ===========================================================================
// Fallback fp32 path (round-1, proven): used only if ws_size < WS_NEED
// ===========================================================================
#define KC 64
#define LSTR 68
__global__ __launch_bounds__(256) void qk_fused(
    const float* __restrict__ x,
    const float* __restrict__ qw, const float* __restrict__ qg,
    const float* __restrict__ qbe, const float* __restrict__ qm,
    const float* __restrict__ qva,
    const float* __restrict__ kw, const float* __restrict__ kg,
    const float* __restrict__ kbe, const float* __restrict__ km,
    const float* __restrict__ kva,
    unsigned char* __restrict__ y)
{
    __shared__ float xs[KC * LSTR];
    __shared__ float qws[48 * LSTR];
    __shared__ float kws[48 * LSTR];
    __shared__ float hsum[16 * 64];
    const int tid = threadIdx.x, bid = blockIdx.x;
    const int b = bid >> 5, head = (bid >> 2) & 7, n0 = (bid & 3) << 6;
    const int dg = tid >> 4, nl = (tid & 15) << 2;
    float q_inv[3], q_mu[3], q_b[3], k_inv[3], k_mu[3], k_b[3];
#pragma unroll
    for (int i = 0; i < 3; ++i) {
        int d = head * 48 + dg * 3 + i;
        q_inv[i] = qg[d] / sqrtf(qva[d] + 1e-5f); q_mu[i] = qm[d]; q_b[i] = qbe[d];
        k_inv[i] = kg[d] / sqrtf(kva[d] + 1e-5f); k_mu[i] = km[d]; k_b[i] = kbe[d];
    }
    float vq[3][4] = {}, vk[3][4] = {}, va[4] = {};
    for (int t = 0; t < TT; ++t) {
        float accq[3][4] = {}, acck[3][4] = {};
        for (int kc = 0; kc < CC / KC; ++kc) {
            const int c0 = kc * KC;
            __syncthreads();
#pragma unroll
            for (int p = 0; p < 4; ++p) {
                int q4 = tid + p * 256, cc = q4 >> 4, nn = (q4 & 15) << 2;
                *(float4*)&xs[cc * LSTR + nn] =
                    *(const float4*)&x[((size_t)(t * BB + b) * CC + c0 + cc) * NN + n0 + nn];
            }
#pragma unroll
            for (int p = 0; p < 3; ++p) {
                int q4 = tid + p * 256, dl = q4 >> 4, cc = (q4 & 15) << 2;
                *(float4*)&qws[dl * LSTR + cc] = *(const float4*)&qw[(head * 48 + dl) * CC + c0 + cc];
                *(float4*)&kws[dl * LSTR + cc] = *(const float4*)&kw[(head * 48 + dl) * CC + c0 + cc];
            }
            __syncthreads();
#pragma unroll
            for (int cq = 0; cq < KC / 4; ++cq) {
                float xv[4][4];
#pragma unroll
                for (int uu = 0; uu < 4; ++uu)
                    *(float4*)&xv[uu][0] = *(const float4*)&xs[(cq * 4 + uu) * LSTR + nl];
#pragma unroll
                for (int i = 0; i < 3; ++i) {
                    float qv[4], kv[4];
                    *(float4*)&qv[0] = *(const float4*)&qws[(dg * 3 + i) * LSTR + cq * 4];
                    *(float4*)&kv[0] = *(const float4*)&kws[(dg * 3 + i) * LSTR + cq * 4];
#pragma unroll
                    for (int uu = 0; uu < 4; ++uu)
#pragma unroll
                        for (int jj = 0; jj < 4; ++jj) {
                            accq[i][jj] = fmaf(qv[uu], xv[uu][jj], accq[i][jj]);
                            acck[i][jj] = fmaf(kv[uu], xv[uu][jj], acck[i][jj]);
                        }
                }
            }
        }
        float part[4] = {0.f, 0.f, 0.f, 0.f};
        float ksp[3][4];
#pragma unroll
        for (int i = 0; i < 3; ++i)
#pragma unroll
            for (int jj = 0; jj < 4; ++jj) {
                float bnq = (accq[i][jj] - q_mu[i]) * q_inv[i] + q_b[i];
                float hq = vq[i][jj] + (bnq - vq[i][jj]) * 0.5f;
                float sq = (hq - 1.0f >= 0.0f) ? 1.0f : 0.0f;
                vq[i][jj] = hq * (1.0f - sq); part[jj] += sq;
                float bnk = (acck[i][jj] - k_mu[i]) * k_inv[i] + k_b[i];
                float hk = vk[i][jj] + (bnk - vk[i][jj]) * 0.5f;
                float sk = (hk - 1.0f >= 0.0f) ? 1.0f : 0.0f;
                vk[i][jj] = hk * (1.0f - sk); ksp[i][jj] = sk;
            }
#pragma unroll
        for (int jj = 0; jj < 4; ++jj) hsum[dg * 64 + nl + jj] = part[jj];
        __syncthreads();
        float attn[4];
#pragma unroll
        for (int jj = 0; jj < 4; ++jj) {
            float tot = 0.f;
#pragma unroll
            for (int g = 0; g < 16; ++g) tot += hsum[g * 64 + nl + jj];
            float ha = va[jj] + (tot - va[jj]) * 0.5f;
            float sa = (ha - 0.5f >= 0.0f) ? 1.0f : 0.0f;
            va[jj] = ha * (1.0f - sa); attn[jj] = sa;
        }
#pragma unroll
        for (int i = 0; i < 3; ++i) {
            uchar4 yo;
            yo.x = (unsigned char)(attn[0] * ksp[i][0]);
            yo.y = (unsigned char)(attn[1] * ksp[i][1]);
            yo.z = (unsigned char)(attn[2] * ksp[i][2]);
            yo.w = (unsigned char)(attn[3] * ksp[i][3]);
            *(uchar4*)&((unsigned char*)y)[((size_t)(t * BB + b) * CC + head * 48 + dg * 3 + i) * NN + n0 + nl] = yo;
        }
    }
}

__global__ __launch_bounds__(256) void proj_fused(
    const unsigned char* __restrict__ yin,
    const float* __restrict__ pw, const float* __restrict__ pg,
    const float* __restrict__ pbe, const float* __restrict__ pm,
    const float* __restrict__ pva, const float* __restrict__ pbias,
    float* __restrict__ out)
{
    __shared__ float ys[KC * LSTR];
    __shared__ float pws[64 * LSTR];
    const int tid = threadIdx.x, bid = blockIdx.x;
    const int b = bid / 24, r = bid % 24, d0 = (r >> 2) * 64, n0 = (r & 3) << 6;
    const int dg = tid >> 4, nl = (tid & 15) << 2;
    float inv[4], mu[4], be[4], bi[4];
#pragma unroll
    for (int i = 0; i < 4; ++i) {
        int d = d0 + dg * 4 + i;
        inv[i] = pg[d] / sqrtf(pva[d] + 1e-5f);
        mu[i] = pm[d]; be[i] = pbe[d]; bi[i] = pbias[d];
    }
    float vvv[4][4] = {};
    for (int t = 0; t < TT; ++t) {
        float acc[4][4] = {};
        for (int kc = 0; kc < CC / KC; ++kc) {
            const int c0 = kc * KC;
            __syncthreads();
#pragma unroll
            for (int p = 0; p < 4; ++p) {
                int q4 = tid + p * 256, cc = q4 >> 4, nn = (q4 & 15) << 2;
                unsigned int w = *(const unsigned int*)&yin[((size_t)(t * BB + b) * CC + c0 + cc) * NN + n0 + nn];
                ys[cc * LSTR + nn + 0] = (float)(w & 0xff);
                ys[cc * LSTR + nn + 1] = (float)((w >> 8) & 0xff);
                ys[cc * LSTR + nn + 2] = (float)((w >> 16) & 0xff);
                ys[cc * LSTR + nn + 3] = (float)(w >> 24);
                *(float4*)&pws[cc * LSTR + nn] = *(const float4*)&pw[(d0 + cc) * CC + c0 + nn];
            }
            __syncthreads();
#pragma unroll
            for (int cq = 0; cq < KC / 4; ++cq) {
                float xv[4][4];
#pragma unroll
                for (int uu = 0; uu < 4; ++uu)
                    *(float4*)&xv[uu][0] = *(const float4*)&ys[(cq * 4 + uu) * LSTR + nl];
#pragma unroll
                for (int i = 0; i < 4; ++i) {
                    float pv[4];
                    *(float4*)&pv[0] = *(const float4*)&pws[(dg * 4 + i) * LSTR + cq * 4];
#pragma unroll
                    for (int uu = 0; uu < 4; ++uu)
#pragma unroll
                        for (int jj = 0; jj < 4; ++jj)
                            acc[i][jj] = fmaf(pv[uu], xv[uu][jj], acc[i][jj]);
                }
            }
        }
#pragma unroll
        for (int i = 0; i < 4; ++i) {
            float res[4];
#pragma unroll
            for (int jj = 0; jj < 4; ++jj) {
                float z = acc[i][jj] + bi[i];
                float bnv = (z - mu[i]) * inv[i] + be[i];
                float h = vvv[i][jj] + (bnv - vvv[i][jj]) * 0.5f;
                float sx = (h - 1.0f >= 0.0f) ? 1.0f : 0.0f;
                vvv[i][jj] = h * (1.0f - sx);
                res[jj] = sx;
            }
            *(float4*)&out[((size_t)(t * BB + b) * CC + d0 + dg * 4 + i) * NN + n0 + nl] = *(float4*)&res[0];
        }
    }
}

extern "C" void kernel_launch(void* const* d_in, const int* in_sizes, int n_in,
                              void* d_out, int out_size, void* d_ws, size_t ws_size,
                              hipStream_t stream)
{
    const float* x     = (const float*)d_in[0];
    const float* qw    = (const float*)d_in[1];
    const float* qg    = (const float*)d_in[2];
    const float* qbe   = (const float*)d_in[3];
    const float* qm    = (const float*)d_in[4];
    const float* qva   = (const float*)d_in[5];
    const float* kw    = (const float*)d_in[6];
    const float* kg    = (const float*)d_in[7];
    const float* kbe   = (const float*)d_in[8];
    const float* km    = (const float*)d_in[9];
    const float* kva   = (const float*)d_in[10];
    const float* pw    = (const float*)d_in[11];
    const float* pg    = (const float*)d_in[12];
    const float* pbe   = (const float*)d_in[13];
    const float* pm    = (const float*)d_in[14];
    const float* pva   = (const float*)d_in[15];
    const float* pbias = (const float*)d_in[16];
    float* out = (float*)d_out;

    if (ws_size >= (size_t)WS_NEED) {
        char* w = (char*)d_ws;
        _Float16* x0  = (_Float16*)(w);
        _Float16* x1  = (_Float16*)(w + WS_X1);
        _Float16* wsp = (_Float16*)(w + WS_WSP);
        _Float16* pw0 = wsp + 4 * 147456;
        _Float16* pw1 = wsp + 5 * 147456;
        _Float16* yf  = (_Float16*)(w + WS_Y);

        prep<<<3288, 256, 0, stream>>>(x, qw, kw, pw, x0, x1, wsp);
        qk_mfma<<<1024, 256, 0, stream>>>(x0, x1, wsp, qg, qbe, qm, qva,
                                          kg, kbe, km, kva, yf);
        proj_mfma<<<1024, 256, 0, stream>>>(yf, pw0, pw1, pg, pbe, pm, pva,
                                            pbias, out);
    } else {
        unsigned char* y = (unsigned char*)d_ws;
        qk_fused<<<BB * 8 * (NN / 64), 256, 0, stream>>>(
            x, qw, qg, qbe, qm, qva, kw, kg, kbe, km, kva, y);
        proj_fused<<<BB * (CC / 64) * (NN / 64), 256, 0, stream>>>(
            y, pw, pg, pbe, pm, pva, pbias, out);
    }
}

// Round 12
// 213.205 us; speedup vs baseline: 3.5801x; 3.5801x over previous
//
#include <hip/hip_runtime.h>

typedef _Float16 f16x8 __attribute__((ext_vector_type(8)));
typedef _Float16 f16x4 __attribute__((ext_vector_type(4)));
typedef float    f32x4 __attribute__((ext_vector_type(4)));

#define TT 4
#define BB 32
#define CC 384
#define NN 256

// ---- ws layout (bytes) ----
// x0f f16 frag-major [(t*32+b)*16+n16][12 kc][64 lane][8] : 0        .. 25165824
// x1f                                                     : 25165824 .. 50331648
// wsp f16 frag-major weights [q0,q1,k0,k1,p0,p1], each
//     [288 frag = h*36+dt*12+kc][64 lane][8] = 147456 el  : 50331648 .. 52101120
//     (p0/p1 K-columns permuted to y's channel order)
// y   f16 frag-major [(t*32+b)*16+n16][12 kc][64][8]      : 52101120 .. 77266944
#define WS_X1   25165824
#define WS_WSP  50331648
#define WS_Y    52101120
#define WS_NEED 77266944

// ---------------------------------------------------------------------------
// prep (merged): blocks 0..3071 = x transpose+split; 3072..3287 = weights.
// (round-9/10 proven version, verbatim)
// ---------------------------------------------------------------------------
__global__ __launch_bounds__(256) void prep(
    const float* __restrict__ x,
    const float* __restrict__ qw, const float* __restrict__ kw,
    const float* __restrict__ pw,
    _Float16* __restrict__ x0, _Float16* __restrict__ x1,
    _Float16* __restrict__ wsp)
{
    __shared__ float xs[64 * 65];
    const int tid = threadIdx.x;
    int bid = blockIdx.x;

    if (bid >= 3072) {
        // ---- weight prep: frag-major f16 hi/lo tables ----
        int gid   = (bid - 3072) * 256 + tid;        // 0..55295
        int which = gid / 18432;                     // 0=q 1=k 2=p
        int sid   = gid % 18432;
        int frag  = sid >> 6;                        // 0..287
        int lane  = sid & 63;
        int h  = frag / 36;
        int rm = frag % 36;
        int dt = rm / 12, kc = rm % 12;
        int m16 = lane & 15, quad = lane >> 4;
        int d = h * 48 + dt * 16 + m16;

        const float* src = (which == 0) ? qw : (which == 1) ? kw : pw;
        _Float16* o0 = wsp + (size_t)which * 294912;
        _Float16* o1 = o0 + 147456;

        f16x8 h0, h1;
#pragma unroll
        for (int jj = 0; jj < 8; ++jj) {
            int cp = kc * 32 + quad * 8 + jj;
            int c;
            if (which == 2) {
                int hp = cp / 48, w = cp % 48;
                int qp = w / 12, r12 = w % 12;
                int sl = r12 >> 2, rr = r12 & 3;
                c = hp * 48 + sl * 16 + qp * 4 + rr;  // inverse permutation
            } else {
                c = cp;
            }
            float v = src[d * CC + c];
            _Float16 a = (_Float16)v;
            h0[jj] = a; h1[jj] = (_Float16)(v - (float)a);
        }
        size_t off = (size_t)frag * 512 + lane * 8;
        *(f16x8*)(o0 + off) = h0;
        *(f16x8*)(o1 + off) = h1;
        return;
    }

    // ---- x prep: [t][b][c][n] fp32 -> frag-major f16 hi/lo ----
    int tb = bid / 24, r = bid % 24;
    int c0 = (r >> 2) * 64, n0 = (r & 3) * 64;

#pragma unroll
    for (int p = 0; p < 4; ++p) {
        int c  = (tid >> 4) + p * 16;
        int nl = (tid & 15) * 4;
        float4 v = *(const float4*)&x[((size_t)tb * CC + c0 + c) * NN + n0 + nl];
        *(float4*)&xs[c * 65 + nl] = v;
    }
    __syncthreads();
#pragma unroll
    for (int p = 0; p < 2; ++p) {
        int sid  = p * 256 + tid;
        int frag = sid >> 6;
        int lane = sid & 63;
        int kcl  = frag & 1, n16l = frag >> 1;
        int m16 = lane & 15, quad = lane >> 4;
        int n_local = n16l * 16 + m16;
        int c_local = kcl * 32 + quad * 8;
        f16x8 h0, h1;
#pragma unroll
        for (int jj = 0; jj < 8; ++jj) {
            float v = xs[(c_local + jj) * 65 + n_local];
            _Float16 a = (_Float16)v;
            h0[jj] = a; h1[jj] = (_Float16)(v - (float)a);
        }
        size_t gf = ((size_t)tb * 16 + (n0 >> 4) + n16l) * 12 + (c0 >> 5) + kcl;
        size_t off = gf * 512 + lane * 8;
        *(f16x8*)(x0 + off) = h0;
        *(f16x8*)(x1 + off) = h1;
    }
}

// ---- helpers for software-pipelined qk main loop (round-8 exact) ----
__device__ __forceinline__ void qk_loadx(
    const _Float16* __restrict__ x0, const _Float16* __restrict__ x1,
    const size_t* fxb, int kc, f16x8 bx[4][2])
{
#pragma unroll
    for (int t = 0; t < 4; ++t) {
        bx[t][0] = *(const f16x8*)(x0 + fxb[t] + kc * 512);
        bx[t][1] = *(const f16x8*)(x1 + fxb[t] + kc * 512);
    }
}

__device__ __forceinline__ void qk_step(
    const _Float16* __restrict__ wq0, const _Float16* __restrict__ wq1,
    const _Float16* __restrict__ wk0, const _Float16* __restrict__ wk1,
    size_t fwb, int kc, const f16x8 bx[4][2],
    f32x4 aq[4][3], f32x4 ak[4][3])
{
#pragma unroll
    for (int dt = 0; dt < 3; ++dt) {
        size_t wo = fwb + (size_t)(dt * 12 + kc) * 512;
        f16x8 q0 = *(const f16x8*)(wq0 + wo);
        f16x8 q1 = *(const f16x8*)(wq1 + wo);
        f16x8 k0 = *(const f16x8*)(wk0 + wo);
        f16x8 k1 = *(const f16x8*)(wk1 + wo);
#pragma unroll
        for (int t = 0; t < 4; ++t) {
            f32x4 cq = aq[t][dt];
            cq = __builtin_amdgcn_mfma_f32_16x16x32_f16(q0, bx[t][0], cq, 0, 0, 0);
            cq = __builtin_amdgcn_mfma_f32_16x16x32_f16(q1, bx[t][0], cq, 0, 0, 0);
            cq = __builtin_amdgcn_mfma_f32_16x16x32_f16(q0, bx[t][1], cq, 0, 0, 0);
            aq[t][dt] = cq;
            f32x4 ck = ak[t][dt];
            ck = __builtin_amdgcn_mfma_f32_16x16x32_f16(k0, bx[t][0], ck, 0, 0, 0);
            ck = __builtin_amdgcn_mfma_f32_16x16x32_f16(k1, bx[t][0], ck, 0, 0, 0);
            ck = __builtin_amdgcn_mfma_f32_16x16x32_f16(k0, bx[t][1], ck, 0, 0, 0);
            ak[t][dt] = ck;
        }
    }
}

// ---------------------------------------------------------------------------
// Kernel A: q/k GEMM + BN + LIF + head-sum + attn LIF + y=attn*k (frag-major)
// ROUND-8 EXACT (twice-proven 63-65 us, WRITE = y minimal).
// ---------------------------------------------------------------------------
__global__ __launch_bounds__(256, 2) void qk_mfma(
    const _Float16* __restrict__ x0, const _Float16* __restrict__ x1,
    const _Float16* __restrict__ wsp,
    const float* __restrict__ qg, const float* __restrict__ qbe,
    const float* __restrict__ qm, const float* __restrict__ qva,
    const float* __restrict__ kg, const float* __restrict__ kbe,
    const float* __restrict__ km, const float* __restrict__ kva,
    _Float16* __restrict__ y)
{
    const int tid  = threadIdx.x;
    const int wave = tid >> 6;
    const int lane = tid & 63;
    const int m16  = lane & 15;
    const int quad = lane >> 4;

    int bid = blockIdx.x;
    int r   = bid & 7;
    int hh  = (bid >> 3) & 1;
    int qq  = bid >> 4;                 // 0..63
    int j   = qq * 8 + r;               // 0..511
    int b   = j >> 4;
    int n16 = j & 15;

    const int head = hh * 4 + wave;

    const _Float16* wq0 = wsp;
    const _Float16* wq1 = wsp + 147456;
    const _Float16* wk0 = wsp + 2 * 147456;
    const _Float16* wk1 = wsp + 3 * 147456;

    size_t fxb[4];
#pragma unroll
    for (int t = 0; t < 4; ++t)
        fxb[t] = (((size_t)(t * BB + b) * 16 + n16) * 12) * 512 + lane * 8;
    size_t fwb = ((size_t)head * 36) * 512 + lane * 8;

    f32x4 aq[4][3], ak[4][3];
#pragma unroll
    for (int t = 0; t < 4; ++t)
#pragma unroll
        for (int dt = 0; dt < 3; ++dt) {
            aq[t][dt] = (f32x4){0.f, 0.f, 0.f, 0.f};
            ak[t][dt] = (f32x4){0.f, 0.f, 0.f, 0.f};
        }

    // software pipeline: ping-pong x prefetch, fully unrolled (12 kc)
    f16x8 bxA[4][2], bxB[4][2];
    qk_loadx(x0, x1, fxb, 0, bxA);
#pragma unroll
    for (int kc2 = 0; kc2 < 6; ++kc2) {
        qk_loadx(x0, x1, fxb, 2 * kc2 + 1, bxB);
        qk_step(wq0, wq1, wk0, wk1, fwb, 2 * kc2, bxA, aq, ak);
        if (kc2 < 5)
            qk_loadx(x0, x1, fxb, 2 * kc2 + 2, bxA);
        qk_step(wq0, wq1, wk0, wk1, fwb, 2 * kc2 + 1, bxB, aq, ak);
    }

    // ---- epilogue: sequential LIF over t ----
    f32x4 vq[3], vk[3];
    float va = 0.f;
#pragma unroll
    for (int dt = 0; dt < 3; ++dt) {
        vq[dt] = (f32x4){0.f, 0.f, 0.f, 0.f};
        vk[dt] = (f32x4){0.f, 0.f, 0.f, 0.f};
    }
#pragma unroll
    for (int t = 0; t < 4; ++t) {
        float psum = 0.f;
        f32x4 ks[3];
#pragma unroll
        for (int dt = 0; dt < 3; ++dt) {
            int doff = head * 48 + dt * 16 + quad * 4;
            f32x4 gq  = *(const f32x4*)(qg + doff);
            f32x4 bq  = *(const f32x4*)(qbe + doff);
            f32x4 mq  = *(const f32x4*)(qm + doff);
            f32x4 vq_ = *(const f32x4*)(qva + doff);
            f32x4 gk_ = *(const f32x4*)(kg + doff);
            f32x4 bk_ = *(const f32x4*)(kbe + doff);
            f32x4 mk_ = *(const f32x4*)(km + doff);
            f32x4 vk_ = *(const f32x4*)(kva + doff);
#pragma unroll
            for (int rr = 0; rr < 4; ++rr) {
                float invq = gq[rr] / sqrtf(vq_[rr] + 1e-5f);
                float invk = gk_[rr] / sqrtf(vk_[rr] + 1e-5f);
                float bnq = (aq[t][dt][rr] - mq[rr]) * invq + bq[rr];
                float hq  = vq[dt][rr] + (bnq - vq[dt][rr]) * 0.5f;
                float sq  = (hq - 1.0f >= 0.0f) ? 1.0f : 0.0f;
                vq[dt][rr] = hq * (1.0f - sq);
                psum += sq;
                float bnk = (ak[t][dt][rr] - mk_[rr]) * invk + bk_[rr];
                float hk  = vk[dt][rr] + (bnk - vk[dt][rr]) * 0.5f;
                float sk  = (hk - 1.0f >= 0.0f) ? 1.0f : 0.0f;
                vk[dt][rr] = hk * (1.0f - sk);
                ks[dt][rr] = sk;
            }
        }
        psum += __shfl_xor(psum, 16, 64);     // 4 quads = all 48 d
        psum += __shfl_xor(psum, 32, 64);
        float ha = va + (psum - va) * 0.5f;
        float sa = (ha - 0.5f >= 0.0f) ? 1.0f : 0.0f;
        va = ha * (1.0f - sa);
        float attn = sa;
        // y store into frag-major layout (round-6/8 proven pattern)
        size_t ybase = (((size_t)(t * BB + b) * 16 + n16) * 12) * 512;
#pragma unroll
        for (int dt = 0; dt < 3; ++dt) {
            int c   = head * 48 + quad * 12 + dt * 4;
            int kcy = c >> 5;
            int qp  = (c & 31) >> 3;
            int jj  = c & 7;
            f16x4 hv;
#pragma unroll
            for (int rr = 0; rr < 4; ++rr)
                hv[rr] = (_Float16)(attn * ks[dt][rr]);
            *(f16x4*)(y + ybase + (size_t)kcy * 512 + (m16 + 16 * qp) * 8 + jj) = hv;
        }
    }
}

// ---- proj macros (round-9 proven version, verbatim) ----
#define PJ_LOADY(dst, kcv)                                                   \
    {                                                                        \
        _Pragma("unroll")                                                    \
        for (int t = 0; t < 4; ++t)                                          \
            dst[t] = *(const f16x8*)(pyb[t] + (kcv) * 512 + lo);             \
    }

#define PJ_STEP(kcv, byv)                                                    \
    {                                                                        \
        f16x8 w[2][3];                                                       \
        _Pragma("unroll")                                                    \
        for (int sp = 0; sp < 2; ++sp)                                       \
            _Pragma("unroll")                                                \
            for (int dt = 0; dt < 3; ++dt)                                   \
                w[sp][dt] = *(const f16x8*)(pwt[sp] +                        \
                    (dt * 12 + (kcv)) * 512 + lo);                           \
        _Pragma("unroll")                                                    \
        for (int dt = 0; dt < 3; ++dt) {                                     \
            _Pragma("unroll")                                                \
            for (int t = 0; t < 4; ++t) {                                    \
                f32x4 c = acc[t][dt];                                        \
                c = __builtin_amdgcn_mfma_f32_16x16x32_f16(w[0][dt], byv[t], c, 0, 0, 0); \
                c = __builtin_amdgcn_mfma_f32_16x16x32_f16(w[1][dt], byv[t], c, 0, 0, 0); \
                acc[t][dt] = c;                                              \
            }                                                                \
        }                                                                    \
    }

// ---------------------------------------------------------------------------
// Kernel B: proj GEMM (frag-major) + bias + BN + LIF -> fp32 spikes.
// ROUND-9 EXACT (best measured rest-of-pipeline).
// ---------------------------------------------------------------------------
__global__ __launch_bounds__(256, 2) void proj_mfma(
    const _Float16* __restrict__ y,
    const _Float16* __restrict__ pw0, const _Float16* __restrict__ pw1,
    const float* __restrict__ pg, const float* __restrict__ pbe,
    const float* __restrict__ pm, const float* __restrict__ pva,
    const float* __restrict__ pbias, float* __restrict__ out)
{
    const int tid  = threadIdx.x;
    const int wave = tid >> 6;
    const int lane = tid & 63;
    const int m16  = lane & 15;
    const int quad = lane >> 4;
    const int lo   = lane * 8;

    int bid = blockIdx.x;
    int r   = bid & 7;
    int dgg = (bid >> 3) & 1;
    int qq  = bid >> 4;
    int j   = qq * 8 + r;
    int b   = j >> 4;
    int n16 = j & 15;

    const int dw = dgg * 4 + wave;       // 0..7, d-tile of 48
    const int d0 = dw * 48;

    const _Float16* pyb[4];
#pragma unroll
    for (int t = 0; t < 4; ++t)
        pyb[t] = y + (((size_t)(t * BB + b) * 16 + n16) * 12) * 512;
    const _Float16* pwt[2];
    pwt[0] = pw0 + (size_t)dw * 36 * 512;
    pwt[1] = pw1 + (size_t)dw * 36 * 512;

    f32x4 acc[4][3];
#pragma unroll
    for (int t = 0; t < 4; ++t)
#pragma unroll
        for (int dt = 0; dt < 3; ++dt)
            acc[t][dt] = (f32x4){0.f, 0.f, 0.f, 0.f};

    f16x8 byA[4], byB[4];
    PJ_LOADY(byA, 0)
#pragma unroll
    for (int kc2 = 0; kc2 < 6; ++kc2) {
        PJ_LOADY(byB, 2 * kc2 + 1)
        PJ_STEP(2 * kc2, byA)
        if (kc2 < 5)
            PJ_LOADY(byA, 2 * kc2 + 2)
        PJ_STEP(2 * kc2 + 1, byB)
    }

    // epilogue: bias + BN + LIF (sequential t), store fp32 spikes
    f32x4 vv[3];
#pragma unroll
    for (int dt = 0; dt < 3; ++dt) vv[dt] = (f32x4){0.f, 0.f, 0.f, 0.f};
#pragma unroll
    for (int dt = 0; dt < 3; ++dt) {
        int doff = d0 + dt * 16 + quad * 4;
        f32x4 g_  = *(const f32x4*)(pg + doff);
        f32x4 be  = *(const f32x4*)(pbe + doff);
        f32x4 mu  = *(const f32x4*)(pm + doff);
        f32x4 va_ = *(const f32x4*)(pva + doff);
        f32x4 bi  = *(const f32x4*)(pbias + doff);
        float inv[4];
#pragma unroll
        for (int rr = 0; rr < 4; ++rr)
            inv[rr] = g_[rr] / sqrtf(va_[rr] + 1e-5f);
#pragma unroll
        for (int t = 0; t < 4; ++t) {
#pragma unroll
            for (int rr = 0; rr < 4; ++rr) {
                float z  = acc[t][dt][rr] + bi[rr];
                float bn = (z - mu[rr]) * inv[rr] + be[rr];
                float h  = vv[dt][rr] + (bn - vv[dt][rr]) * 0.5f;
                float sp = (h - 1.0f >= 0.0f) ? 1.0f : 0.0f;
                vv[dt][rr] = h * (1.0f - sp);
                out[((size_t)(t * BB + b) * CC + doff + rr) * NN +
                    n16 * 16 + m16] = sp;
            }
        }
    }
}

// ===========================================================================
// Fallback fp32 path (round-1, proven): used only if ws_size < WS_NEED
// ===========================================================================
#define KC 64
#define LSTR 68
__global__ __launch_bounds__(256) void qk_fused(
    const float* __restrict__ x,
    const float* __restrict__ qw, const float* __restrict__ qg,
    const float* __restrict__ qbe, const float* __restrict__ qm,
    const float* __restrict__ qva,
    const float* __restrict__ kw, const float* __restrict__ kg,
    const float* __restrict__ kbe, const float* __restrict__ km,
    const float* __restrict__ kva,
    unsigned char* __restrict__ y)
{
    __shared__ float xs[KC * LSTR];
    __shared__ float qws[48 * LSTR];
    __shared__ float kws[48 * LSTR];
    __shared__ float hsum[16 * 64];
    const int tid = threadIdx.x, bid = blockIdx.x;
    const int b = bid >> 5, head = (bid >> 2) & 7, n0 = (bid & 3) << 6;
    const int dg = tid >> 4, nl = (tid & 15) << 2;
    float q_inv[3], q_mu[3], q_b[3], k_inv[3], k_mu[3], k_b[3];
#pragma unroll
    for (int i = 0; i < 3; ++i) {
        int d = head * 48 + dg * 3 + i;
        q_inv[i] = qg[d] / sqrtf(qva[d] + 1e-5f); q_mu[i] = qm[d]; q_b[i] = qbe[d];
        k_inv[i] = kg[d] / sqrtf(kva[d] + 1e-5f); k_mu[i] = km[d]; k_b[i] = kbe[d];
    }
    float vq[3][4] = {}, vk[3][4] = {}, va[4] = {};
    for (int t = 0; t < TT; ++t) {
        float accq[3][4] = {}, acck[3][4] = {};
        for (int kc = 0; kc < CC / KC; ++kc) {
            const int c0 = kc * KC;
            __syncthreads();
#pragma unroll
            for (int p = 0; p < 4; ++p) {
                int q4 = tid + p * 256, cc = q4 >> 4, nn = (q4 & 15) << 2;
                *(float4*)&xs[cc * LSTR + nn] =
                    *(const float4*)&x[((size_t)(t * BB + b) * CC + c0 + cc) * NN + n0 + nn];
            }
#pragma unroll
            for (int p = 0; p < 3; ++p) {
                int q4 = tid + p * 256, dl = q4 >> 4, cc = (q4 & 15) << 2;
                *(float4*)&qws[dl * LSTR + cc] = *(const float4*)&qw[(head * 48 + dl) * CC + c0 + cc];
                *(float4*)&kws[dl * LSTR + cc] = *(const float4*)&kw[(head * 48 + dl) * CC + c0 + cc];
            }
            __syncthreads();
#pragma unroll
            for (int cq = 0; cq < KC / 4; ++cq) {
                float xv[4][4];
#pragma unroll
                for (int uu = 0; uu < 4; ++uu)
                    *(float4*)&xv[uu][0] = *(const float4*)&xs[(cq * 4 + uu) * LSTR + nl];
#pragma unroll
                for (int i = 0; i < 3; ++i) {
                    float qv[4], kv[4];
                    *(float4*)&qv[0] = *(const float4*)&qws[(dg * 3 + i) * LSTR + cq * 4];
                    *(float4*)&kv[0] = *(const float4*)&kws[(dg * 3 + i) * LSTR + cq * 4];
#pragma unroll
                    for (int uu = 0; uu < 4; ++uu)
#pragma unroll
                        for (int jj = 0; jj < 4; ++jj) {
                            accq[i][jj] = fmaf(qv[uu], xv[uu][jj], accq[i][jj]);
                            acck[i][jj] = fmaf(kv[uu], xv[uu][jj], acck[i][jj]);
                        }
                }
            }
        }
        float part[4] = {0.f, 0.f, 0.f, 0.f};
        float ksp[3][4];
#pragma unroll
        for (int i = 0; i < 3; ++i)
#pragma unroll
            for (int jj = 0; jj < 4; ++jj) {
                float bnq = (accq[i][jj] - q_mu[i]) * q_inv[i] + q_b[i];
                float hq = vq[i][jj] + (bnq - vq[i][jj]) * 0.5f;
                float sq = (hq - 1.0f >= 0.0f) ? 1.0f : 0.0f;
                vq[i][jj] = hq * (1.0f - sq); part[jj] += sq;
                float bnk = (acck[i][jj] - k_mu[i]) * k_inv[i] + k_b[i];
                float hk = vk[i][jj] + (bnk - vk[i][jj]) * 0.5f;
                float sk = (hk - 1.0f >= 0.0f) ? 1.0f : 0.0f;
                vk[i][jj] = hk * (1.0f - sk); ksp[i][jj] = sk;
            }
#pragma unroll
        for (int jj = 0; jj < 4; ++jj) hsum[dg * 64 + nl + jj] = part[jj];
        __syncthreads();
        float attn[4];
#pragma unroll
        for (int jj = 0; jj < 4; ++jj) {
            float tot = 0.f;
#pragma unroll
            for (int g = 0; g < 16; ++g) tot += hsum[g * 64 + nl + jj];
            float ha = va[jj] + (tot - va[jj]) * 0.5f;
            float sa = (ha - 0.5f >= 0.0f) ? 1.0f : 0.0f;
            va[jj] = ha * (1.0f - sa); attn[jj] = sa;
        }
#pragma unroll
        for (int i = 0; i < 3; ++i) {
            uchar4 yo;
            yo.x = (unsigned char)(attn[0] * ksp[i][0]);
            yo.y = (unsigned char)(attn[1] * ksp[i][1]);
            yo.z = (unsigned char)(attn[2] * ksp[i][2]);
            yo.w = (unsigned char)(attn[3] * ksp[i][3]);
            *(uchar4*)&((unsigned char*)y)[((size_t)(t * BB + b) * CC + head * 48 + dg * 3 + i) * NN + n0 + nl] = yo;
        }
    }
}

__global__ __launch_bounds__(256) void proj_fused(
    const unsigned char* __restrict__ yin,
    const float* __restrict__ pw, const float* __restrict__ pg,
    const float* __restrict__ pbe, const float* __restrict__ pm,
    const float* __restrict__ pva, const float* __restrict__ pbias,
    float* __restrict__ out)
{
    __shared__ float ys[KC * LSTR];
    __shared__ float pws[64 * LSTR];
    const int tid = threadIdx.x, bid = blockIdx.x;
    const int b = bid / 24, r = bid % 24, d0 = (r >> 2) * 64, n0 = (r & 3) << 6;
    const int dg = tid >> 4, nl = (tid & 15) << 2;
    float inv[4], mu[4], be[4], bi[4];
#pragma unroll
    for (int i = 0; i < 4; ++i) {
        int d = d0 + dg * 4 + i;
        inv[i] = pg[d] / sqrtf(pva[d] + 1e-5f);
        mu[i] = pm[d]; be[i] = pbe[d]; bi[i] = pbias[d];
    }
    float vvv[4][4] = {};
    for (int t = 0; t < TT; ++t) {
        float acc[4][4] = {};
        for (int kc = 0; kc < CC / KC; ++kc) {
            const int c0 = kc * KC;
            __syncthreads();
#pragma unroll
            for (int p = 0; p < 4; ++p) {
                int q4 = tid + p * 256, cc = q4 >> 4, nn = (q4 & 15) << 2;
                unsigned int w = *(const unsigned int*)&yin[((size_t)(t * BB + b) * CC + c0 + cc) * NN + n0 + nn];
                ys[cc * LSTR + nn + 0] = (float)(w & 0xff);
                ys[cc * LSTR + nn + 1] = (float)((w >> 8) & 0xff);
                ys[cc * LSTR + nn + 2] = (float)((w >> 16) & 0xff);
                ys[cc * LSTR + nn + 3] = (float)(w >> 24);
                *(float4*)&pws[cc * LSTR + nn] = *(const float4*)&pw[(d0 + cc) * CC + c0 + nn];
            }
            __syncthreads();
#pragma unroll
            for (int cq = 0; cq < KC / 4; ++cq) {
                float xv[4][4];
#pragma unroll
                for (int uu = 0; uu < 4; ++uu)
                    *(float4*)&xv[uu][0] = *(const float4*)&ys[(cq * 4 + uu) * LSTR + nl];
#pragma unroll
                for (int i = 0; i < 4; ++i) {
                    float pv[4];
                    *(float4*)&pv[0] = *(const float4*)&pws[(dg * 4 + i) * LSTR + cq * 4];
#pragma unroll
                    for (int uu = 0; uu < 4; ++uu)
#pragma unroll
                        for (int jj = 0; jj < 4; ++jj)
                            acc[i][jj] = fmaf(pv[uu], xv[uu][jj], acc[i][jj]);
                }
            }
        }
#pragma unroll
        for (int i = 0; i < 4; ++i) {
            float res[4];
#pragma unroll
            for (int jj = 0; jj < 4; ++jj) {
                float z = acc[i][jj] + bi[i];
                float bnv = (z - mu[i]) * inv[i] + be[i];
                float h = vvv[i][jj] + (bnv - vvv[i][jj]) * 0.5f;
                float sx = (h - 1.0f >= 0.0f) ? 1.0f : 0.0f;
                vvv[i][jj] = h * (1.0f - sx);
                res[jj] = sx;
            }
            *(float4*)&out[((size_t)(t * BB + b) * CC + d0 + dg * 4 + i) * NN + n0 + nl] = *(float4*)&res[0];
        }
    }
}

extern "C" void kernel_launch(void* const* d_in, const int* in_sizes, int n_in,
                              void* d_out, int out_size, void* d_ws, size_t ws_size,
                              hipStream_t stream)
{
    const float* x     = (const float*)d_in[0];
    const float* qw    = (const float*)d_in[1];
    const float* qg    = (const float*)d_in[2];
    const float* qbe   = (const float*)d_in[3];
    const float* qm    = (const float*)d_in[4];
    const float* qva   = (const float*)d_in[5];
    const float* kw    = (const float*)d_in[6];
    const float* kg    = (const float*)d_in[7];
    const float* kbe   = (const float*)d_in[8];
    const float* km    = (const float*)d_in[9];
    const float* kva   = (const float*)d_in[10];
    const float* pw    = (const float*)d_in[11];
    const float* pg    = (const float*)d_in[12];
    const float* pbe   = (const float*)d_in[13];
    const float* pm    = (const float*)d_in[14];
    const float* pva   = (const float*)d_in[15];
    const float* pbias = (const float*)d_in[16];
    float* out = (float*)d_out;

    if (ws_size >= (size_t)WS_NEED) {
        char* w = (char*)d_ws;
        _Float16* x0  = (_Float16*)(w);
        _Float16* x1  = (_Float16*)(w + WS_X1);
        _Float16* wsp = (_Float16*)(w + WS_WSP);
        _Float16* pw0 = wsp + 4 * 147456;
        _Float16* pw1 = wsp + 5 * 147456;
        _Float16* yf  = (_Float16*)(w + WS_Y);

        prep<<<3288, 256, 0, stream>>>(x, qw, kw, pw, x0, x1, wsp);
        qk_mfma<<<1024, 256, 0, stream>>>(x0, x1, wsp, qg, qbe, qm, qva,
                                          kg, kbe, km, kva, yf);
        proj_mfma<<<1024, 256, 0, stream>>>(yf, pw0, pw1, pg, pbe, pm, pva,
                                            pbias, out);
    } else {
        unsigned char* y = (unsigned char*)d_ws;
        qk_fused<<<BB * 8 * (NN / 64), 256, 0, stream>>>(
            x, qw, qg, qbe, qm, qva, kw, kg, kbe, km, kva, y);
        proj_fused<<<BB * (CC / 64) * (NN / 64), 256, 0, stream>>>(
            y, pw, pg, pbe, pm, pva, pbias, out);
    }
}